// Round 1
// baseline (4077.825 us; speedup 1.0000x reference)
//
#include <hip/hip_runtime.h>

// Capsule routing, f32.
// B=32, Nin=2048, Din=16, Nout=64, Dout=32, 3 routing iterations.
// Never materialize u_hat (537MB); recompute per routing pass from W (268MB).

#define CB    32      // batch
#define NIN   2048
#define DIN   16
#define NOUT  64
#define DOUT  32
#define CHUNK 64
#define NCHUNK (NIN / CHUNK)   // 32

// Pass kernel. IT=0: uniform c (=1/64). IT=1: blog = u.v1 (store blog).
// IT=2: blog = blog_in + u.v2 (no store).
// Block = 256 threads handles (b, i-chunk). Thread t owns j=t>>2, d in [ (t&3)*8, +8 ).
template <int IT>
__global__ __launch_bounds__(256) void caps_pass(
    const float* __restrict__ x,        // [B, NIN, DIN]
    const float* __restrict__ W,        // [NIN, NOUT, DOUT, DIN]
    const float* __restrict__ v_prev,   // [B, NOUT, DOUT]   (IT>0)
    const float* __restrict__ blog_in,  // [B, NIN, NOUT]    (IT==2)
    float* __restrict__ blog_out,       // [B, NIN, NOUT]    (IT==1)
    float* __restrict__ s_partial)      // [B, NCHUNK, NOUT*DOUT]
{
    const int blk   = blockIdx.x;       // chunk*CB + b  (consecutive blocks share chunk)
    const int b     = blk % CB;
    const int chunk = blk / CB;
    const int t     = threadIdx.x;      // 0..255
    const int j     = t >> 2;           // 0..63
    const int d0    = (t & 3) * 8;      // 0,8,16,24

    __shared__ float sh_v[NOUT * DOUT];   // 8KB (IT>0)
    __shared__ float sh_x[CHUNK * DIN];   // 4KB
    __shared__ float sh_bl[NOUT];
    __shared__ float sh_red[2];

    if (IT > 0) {
        for (int idx = t; idx < NOUT * DOUT; idx += 256)
            sh_v[idx] = v_prev[b * NOUT * DOUT + idx];
    }
    for (int idx = t; idx < CHUNK * DIN; idx += 256)
        sh_x[idx] = x[(size_t)b * NIN * DIN + (size_t)chunk * CHUNK * DIN + idx];
    __syncthreads();

    float vreg[8];
    if (IT > 0) {
#pragma unroll
        for (int r = 0; r < 8; ++r) vreg[r] = sh_v[j * DOUT + d0 + r];
    }

    float sacc[8] = {0.f, 0.f, 0.f, 0.f, 0.f, 0.f, 0.f, 0.f};

    for (int ii = 0; ii < CHUNK; ++ii) {
        const int i = chunk * CHUNK + ii;

        // x[b,i,:] from LDS (broadcast reads)
        float xr[DIN];
#pragma unroll
        for (int k = 0; k < DIN; ++k) xr[k] = sh_x[ii * DIN + k];

        // u_hat[j, d0..d0+7] : 8 rows x 16 k, 512B contiguous per thread
        const float4* wp = (const float4*)(W
            + (size_t)i * (NOUT * DOUT * DIN)
            + (size_t)j * (DOUT * DIN)
            + (size_t)d0 * DIN);
        float uh[8];
#pragma unroll
        for (int r = 0; r < 8; ++r) {
            float acc = 0.f;
#pragma unroll
            for (int q = 0; q < 4; ++q) {
                float4 w = wp[r * 4 + q];
                acc += w.x * xr[4 * q + 0] + w.y * xr[4 * q + 1]
                     + w.z * xr[4 * q + 2] + w.w * xr[4 * q + 3];
            }
            uh[r] = acc;
        }

        float c;
        if (IT == 0) {
            c = 1.0f / 64.0f;
        } else {
            // b-logit: dot over all 32 d (4-lane butterfly within j-group)
            float dot = 0.f;
#pragma unroll
            for (int r = 0; r < 8; ++r) dot += uh[r] * vreg[r];
            dot += __shfl_xor(dot, 1);
            dot += __shfl_xor(dot, 2);

            float bl = dot;
            if (IT == 2) bl += blog_in[((size_t)b * NIN + i) * NOUT + j];
            if (IT == 1) {
                if ((t & 3) == 0) blog_out[((size_t)b * NIN + i) * NOUT + j] = bl;
            }

            // softmax over the 64 j's (block-wide)
            if ((t & 3) == 0) sh_bl[j] = bl;
            __syncthreads();
            if (t < 64) {
                float m = sh_bl[t];
#pragma unroll
                for (int o = 32; o; o >>= 1) m = fmaxf(m, __shfl_xor(m, o));
                float e = __expf(sh_bl[t] - m);
#pragma unroll
                for (int o = 32; o; o >>= 1) e += __shfl_xor(e, o);
                if (t == 0) { sh_red[0] = m; sh_red[1] = e; }
            }
            __syncthreads();
            c = __expf(bl - sh_red[0]) / sh_red[1];
        }

#pragma unroll
        for (int r = 0; r < 8; ++r) sacc[r] += c * uh[r];
    }

    // thread t's flat (j,d) range is exactly [t*8, t*8+8) -> coalesced
    float* sp = s_partial + ((size_t)b * NCHUNK + chunk) * (NOUT * DOUT) + t * 8;
#pragma unroll
    for (int r = 0; r < 8; ++r) sp[r] = sacc[r];
}

// Reduce partials over chunks, add bias, squash. One wave per (b,j).
__global__ __launch_bounds__(64) void caps_squash(
    const float* __restrict__ s_partial,  // [B, NCHUNK, NOUT*DOUT]
    const float* __restrict__ bias,       // [NOUT, DOUT]
    float* __restrict__ v_out)            // [B, NOUT, DOUT]
{
    const int bj = blockIdx.x;
    const int b  = bj / NOUT;
    const int j  = bj % NOUT;
    const int t  = threadIdx.x;    // 0..63
    const int d  = t & 31;
    const int h  = t >> 5;

    float sv = 0.f;
    for (int c = h; c < NCHUNK; c += 2)
        sv += s_partial[((size_t)b * NCHUNK + c) * (NOUT * DOUT) + j * DOUT + d];
    sv += __shfl_xor(sv, 32);          // both halves now hold full chunk sum
    sv += bias[j * DOUT + d];

    float sq = sv * sv;
#pragma unroll
    for (int o = 16; o; o >>= 1) sq += __shfl_xor(sq, o);  // sum over 32 d (halves identical)

    float scale = (sq / (1.0f + sq)) * rsqrtf(sq + 1e-9f);
    float v = scale * sv;
    if (t < 32) v_out[((size_t)b * NOUT + j) * DOUT + d] = v;
}

extern "C" void kernel_launch(void* const* d_in, const int* in_sizes, int n_in,
                              void* d_out, int out_size, void* d_ws, size_t ws_size,
                              hipStream_t stream) {
    const float* x    = (const float*)d_in[0];
    const float* W    = (const float*)d_in[1];
    const float* bias = (const float*)d_in[2];
    float* out = (float*)d_out;

    float* blog  = (float*)d_ws;                                // 32*2048*64   = 4,194,304 f (16MB)
    float* spart = blog + (size_t)CB * NIN * NOUT;              // 32*32*2048   = 2,097,152 f (8MB)
    float* vbuf  = spart + (size_t)CB * NCHUNK * NOUT * DOUT;   // 32*64*32     = 65,536 f (256KB)

    dim3 grid(CB * NCHUNK);   // 1024 blocks; consecutive 32 blocks share an i-chunk (L2/L3 reuse of W)
    dim3 blockDim(256);

    // it = 0: uniform coupling
    caps_pass<0><<<grid, blockDim, 0, stream>>>(x, W, nullptr, nullptr, nullptr, spart);
    caps_squash<<<CB * NOUT, 64, 0, stream>>>(spart, bias, vbuf);

    // it = 1: blog = u.v1, store blog
    caps_pass<1><<<grid, blockDim, 0, stream>>>(x, W, vbuf, nullptr, blog, spart);
    caps_squash<<<CB * NOUT, 64, 0, stream>>>(spart, bias, vbuf);

    // it = 2: blog = blog_in + u.v2
    caps_pass<2><<<grid, blockDim, 0, stream>>>(x, W, vbuf, blog, nullptr, spart);
    caps_squash<<<CB * NOUT, 64, 0, stream>>>(spart, bias, out);
}

// Round 2
// 648.755 us; speedup vs baseline: 6.2856x; 6.2856x over previous
//
#include <hip/hip_runtime.h>

// Capsule routing, f32. B=32, Nin=2048, Din=16, Nout=64, Dout=32, 3 iterations.
// Round 1: G=8 batch-group register blocking (W fragment reused 8x from VGPRs)
// + XCD swizzle so all 4 batch-groups of an i-chunk share one XCD's L2.

#define CB    32
#define NIN   2048
#define DIN   16
#define NOUT  64
#define DOUT  32
#define CHUNK 32
#define NCHUNK (NIN / CHUNK)   // 64
#define G     8
#define NBG   (CB / G)         // 4

// Block: 512 threads. t owns j = t>>3 (0..63), d0 = (t&7)*4.
// Per i: load W frag (4 rows x 16 k = 16 float4, kept in regs), reuse across G batches.
template <int IT>
__global__ __launch_bounds__(512, 2) void caps_pass(
    const float* __restrict__ x,        // [B, NIN, DIN]
    const float* __restrict__ W,        // [NIN, NOUT, DOUT, DIN]
    const float* __restrict__ v_prev,   // [B, NOUT, DOUT]   (IT>0)
    const float* __restrict__ blog_in,  // [B, NIN, NOUT]    (IT==2)
    float* __restrict__ blog_out,       // [B, NIN, NOUT]    (IT==1)
    float* __restrict__ s_partial)      // [B, NCHUNK, NOUT*DOUT]
{
    // XCD swizzle: physical p -> (chunk, bg) with p%8 == chunk%8, so the 4
    // batch-groups of a chunk land on the same XCD (chunk W slice ~4.2MB ~ L2).
    const int p     = blockIdx.x;            // 0..255
    const int chunk = (p >> 5) * 8 + (p & 7);
    const int bg    = (p & 31) >> 3;
    const int b0    = bg * G;
    const int t     = threadIdx.x;
    const int j     = t >> 3;
    const int d0    = (t & 7) * 4;
    const int wave  = t >> 6;
    const int lane  = t & 63;

    __shared__ float sh_x[G][CHUNK][DIN];  // 16KB
    __shared__ float sh_bl[G][NOUT];       // 2KB
    __shared__ float sh_red[G][2];

    for (int idx = t; idx < G * CHUNK * DIN; idx += 512) {
        const int bb  = idx >> 9;           // / (CHUNK*DIN)
        const int rem = idx & 511;
        sh_x[0][0][idx] = x[(size_t)(b0 + bb) * NIN * DIN
                            + (size_t)chunk * CHUNK * DIN + rem];
    }

    float vreg[G][4];
    if (IT > 0) {
#pragma unroll
        for (int bb = 0; bb < G; ++bb) {
            const float4 v4 = *(const float4*)(v_prev
                + (size_t)(b0 + bb) * NOUT * DOUT + j * DOUT + d0);
            vreg[bb][0] = v4.x; vreg[bb][1] = v4.y;
            vreg[bb][2] = v4.z; vreg[bb][3] = v4.w;
        }
    }
    __syncthreads();

    float sacc[G][4];
#pragma unroll
    for (int bb = 0; bb < G; ++bb)
#pragma unroll
        for (int r = 0; r < 4; ++r) sacc[bb][r] = 0.f;

    for (int ii = 0; ii < CHUNK; ++ii) {
        const int i = chunk * CHUNK + ii;

        // W fragment: rows d0..d0+3, all 16 k. 256B contiguous per thread.
        const float4* wp = (const float4*)(W
            + (size_t)i * (NOUT * DOUT * DIN)
            + (size_t)j * (DOUT * DIN)
            + (size_t)d0 * DIN);
        float4 wf[16];
#pragma unroll
        for (int q = 0; q < 16; ++q) wf[q] = wp[q];

        // u_hat for all G batches from the register-resident W fragment
        float uh[G][4];
#pragma unroll
        for (int bb = 0; bb < G; ++bb) {
            float xr[DIN];
#pragma unroll
            for (int k = 0; k < DIN; ++k) xr[k] = sh_x[bb][ii][k];
#pragma unroll
            for (int r = 0; r < 4; ++r) {
                float acc = 0.f;
#pragma unroll
                for (int q = 0; q < 4; ++q) {
                    const float4 w = wf[r * 4 + q];
                    acc += w.x * xr[4 * q + 0] + w.y * xr[4 * q + 1]
                         + w.z * xr[4 * q + 2] + w.w * xr[4 * q + 3];
                }
                uh[bb][r] = acc;
            }
        }

        if (IT == 0) {
#pragma unroll
            for (int bb = 0; bb < G; ++bb)
#pragma unroll
                for (int r = 0; r < 4; ++r)
                    sacc[bb][r] += (1.0f / 64.0f) * uh[bb][r];
        } else {
            // b-logit: dot(uh, v) over all 32 d -> butterfly over the 8-lane j-group
            float bl[G];
#pragma unroll
            for (int bb = 0; bb < G; ++bb) {
                float dot = 0.f;
#pragma unroll
                for (int r = 0; r < 4; ++r) dot += uh[bb][r] * vreg[bb][r];
                dot += __shfl_xor(dot, 1);
                dot += __shfl_xor(dot, 2);
                dot += __shfl_xor(dot, 4);
                bl[bb] = dot;
            }
            if (IT == 2) {
#pragma unroll
                for (int bb = 0; bb < G; ++bb)
                    bl[bb] += blog_in[((size_t)(b0 + bb) * NIN + i) * NOUT + j];
            }
            if (IT == 1) {
                if ((t & 7) == 0) {
#pragma unroll
                    for (int bb = 0; bb < G; ++bb)
                        blog_out[((size_t)(b0 + bb) * NIN + i) * NOUT + j] = bl[bb];
                }
            }
            if ((t & 7) == 0) {
#pragma unroll
                for (int bb = 0; bb < G; ++bb) sh_bl[bb][j] = bl[bb];
            }
            __syncthreads();
            // one wave per batch: softmax reduce over the 64 j's
            {
                const float val = sh_bl[wave][lane];
                float m = val;
#pragma unroll
                for (int o = 32; o; o >>= 1) m = fmaxf(m, __shfl_xor(m, o));
                float e = __expf(val - m);
#pragma unroll
                for (int o = 32; o; o >>= 1) e += __shfl_xor(e, o);
                if (lane == 0) { sh_red[wave][0] = m; sh_red[wave][1] = 1.0f / e; }
            }
            __syncthreads();
#pragma unroll
            for (int bb = 0; bb < G; ++bb) {
                const float c = __expf(bl[bb] - sh_red[bb][0]) * sh_red[bb][1];
#pragma unroll
                for (int r = 0; r < 4; ++r) sacc[bb][r] += c * uh[bb][r];
            }
        }
    }

    // thread t's flat (j,d) range is [t*4, t*4+4) -> coalesced float4 stores
#pragma unroll
    for (int bb = 0; bb < G; ++bb) {
        float4 o;
        o.x = sacc[bb][0]; o.y = sacc[bb][1]; o.z = sacc[bb][2]; o.w = sacc[bb][3];
        *(float4*)(s_partial
            + ((size_t)(b0 + bb) * NCHUNK + chunk) * (NOUT * DOUT) + t * 4) = o;
    }
}

// Reduce partials over chunks, add bias, squash. One wave per (b,j).
__global__ __launch_bounds__(64) void caps_squash(
    const float* __restrict__ s_partial,  // [B, NCHUNK, NOUT*DOUT]
    const float* __restrict__ bias,       // [NOUT, DOUT]
    float* __restrict__ v_out)            // [B, NOUT, DOUT]
{
    const int bj = blockIdx.x;
    const int b  = bj / NOUT;
    const int j  = bj % NOUT;
    const int t  = threadIdx.x;    // 0..63
    const int d  = t & 31;
    const int h  = t >> 5;

    float sv = 0.f;
    for (int c = h; c < NCHUNK; c += 2)
        sv += s_partial[((size_t)b * NCHUNK + c) * (NOUT * DOUT) + j * DOUT + d];
    sv += __shfl_xor(sv, 32);
    sv += bias[j * DOUT + d];

    float sq = sv * sv;
#pragma unroll
    for (int o = 16; o; o >>= 1) sq += __shfl_xor(sq, o);

    float scale = (sq / (1.0f + sq)) * rsqrtf(sq + 1e-9f);
    float v = scale * sv;
    if (t < 32) v_out[((size_t)b * NOUT + j) * DOUT + d] = v;
}

extern "C" void kernel_launch(void* const* d_in, const int* in_sizes, int n_in,
                              void* d_out, int out_size, void* d_ws, size_t ws_size,
                              hipStream_t stream) {
    const float* x    = (const float*)d_in[0];
    const float* W    = (const float*)d_in[1];
    const float* bias = (const float*)d_in[2];
    float* out = (float*)d_out;

    float* blog  = (float*)d_ws;                                // 32*2048*64 f = 16MB
    float* spart = blog + (size_t)CB * NIN * NOUT;              // 32*64*2048 f = 16.8MB
    float* vbuf  = spart + (size_t)CB * NCHUNK * NOUT * DOUT;   // 32*64*32 f = 256KB

    dim3 grid(NCHUNK * NBG);   // 256 blocks, 1 per CU
    dim3 blockDim(512);

    caps_pass<0><<<grid, blockDim, 0, stream>>>(x, W, nullptr, nullptr, nullptr, spart);
    caps_squash<<<CB * NOUT, 64, 0, stream>>>(spart, bias, vbuf);

    caps_pass<1><<<grid, blockDim, 0, stream>>>(x, W, vbuf, nullptr, blog, spart);
    caps_squash<<<CB * NOUT, 64, 0, stream>>>(spart, bias, vbuf);

    caps_pass<2><<<grid, blockDim, 0, stream>>>(x, W, vbuf, blog, nullptr, spart);
    caps_squash<<<CB * NOUT, 64, 0, stream>>>(spart, bias, out);
}